// Round 6
// baseline (576.272 us; speedup 1.0000x reference)
//
#include <hip/hip_runtime.h>
#include <hip/hip_cooperative_groups.h>
#include <math.h>

namespace cg = cooperative_groups;

// Problem constants
#define B8   8
#define HW4  196   // 14*14
#define HW5  49    // 7*7
#define HFW  28
#define NPIX 784   // 28*28
#define CAPP 1536
#define D1   38400 // 1536*25
#define NR   64    // B*G
#define NTHREADS 65536  // 256 blocks * 256 threads

typedef short short8 __attribute__((ext_vector_type(8)));
typedef short short4v __attribute__((ext_vector_type(4)));
typedef float floatx16 __attribute__((ext_vector_type(16)));

__device__ __forceinline__ unsigned short f2bf(float f) {
  unsigned u = __float_as_uint(f);
  u += 0x7FFF + ((u >> 16) & 1);
  return (unsigned short)(u >> 16);
}

struct Params {
  const float *x4, *x5, *boxes, *skel;
  const int *group, *label;
  const float *c1w, *c1b, *w2c, *b2c, *w3c, *b3c;
  const float *n1w, *n1b, *n2w, *n2b, *fw1, *fb1, *fw2, *fb2;
  float* out;
  unsigned short *x4T, *x5T, *sknT;
  float *f4T, *f5T, *tap4w, *tap5w, *descw, *roisP, *stats, *out1;
  int *tap4o, *tap5o, *desco;
};

union SharedU {
  float tile[64 * 201];                         // 51,456 B (transpose phase)
  struct {
    unsigned short As[2][8][64][8];             // [buf][ko][m][j]
    unsigned short Bs[2][8][64][8];
  } g;                                          // 32,768 B (gemm phases)
  struct {
    float cw4[16], cw5[16], wgs;
    int co4[16], co5[16];
    float red[8];
  } roi;
  struct {
    float red[8];
    float red2[24];
  } ln;
};

// ---- one 64m x 64n GEMM tile: C[m][n] (+)= sum_{k0..k0+kchunk} A[m][k]*W[n][k] ----
// A bf16 k-contig rows; W fp32 k-contig rows (cvt bf16 at stage). dbuf LDS, BK=64.
__device__ __forceinline__ void gemm_unit(
    SharedU& sh, const unsigned short* __restrict__ A, const float* __restrict__ Bw,
    float* __restrict__ C, int mt, int nt, int k0, int kchunk,
    int K, int N, int Mvalid, bool atomicStore) {
  int t = threadIdx.x;
  int wave = t >> 6, lane = t & 63;
  int wm = wave & 1, wn = wave >> 1;
  const unsigned short* Aptr = A + (size_t)(mt * 64) * K + k0;
  const float* Bptr = Bw + (size_t)(nt * 64) * K + k0;
  short8 areg[2];
  float4 breg[4];
  floatx16 acc;
#pragma unroll
  for (int i = 0; i < 16; i++) acc[i] = 0.f;
  int nkb = kchunk >> 6;

  // prologue: stage kb=0
#pragma unroll
  for (int i = 0; i < 2; i++) {
    int e = t + i * 256;
    areg[i] = *(const short8*)(Aptr + (size_t)(e >> 3) * K + (e & 7) * 8);
  }
#pragma unroll
  for (int i = 0; i < 4; i++) {
    int e = t + i * 256;
    breg[i] = *(const float4*)(Bptr + (size_t)(e >> 4) * K + (e & 15) * 4);
  }
#pragma unroll
  for (int i = 0; i < 2; i++) {
    int e = t + i * 256;
    *(short8*)&sh.g.As[0][e & 7][e >> 3][0] = areg[i];
  }
#pragma unroll
  for (int i = 0; i < 4; i++) {
    int e = t + i * 256;
    short4v v;
    v[0] = (short)f2bf(breg[i].x); v[1] = (short)f2bf(breg[i].y);
    v[2] = (short)f2bf(breg[i].z); v[3] = (short)f2bf(breg[i].w);
    *(short4v*)&sh.g.Bs[0][(e & 15) >> 1][e >> 4][((e & 15) & 1) * 4] = v;
  }
  __syncthreads();

  for (int kb = 0; kb < nkb; kb++) {
    int buf = kb & 1;
    bool more = (kb + 1) < nkb;
    if (more) {
      int kof = (kb + 1) * 64;
#pragma unroll
      for (int i = 0; i < 2; i++) {
        int e = t + i * 256;
        areg[i] = *(const short8*)(Aptr + (size_t)(e >> 3) * K + kof + (e & 7) * 8);
      }
#pragma unroll
      for (int i = 0; i < 4; i++) {
        int e = t + i * 256;
        breg[i] = *(const float4*)(Bptr + (size_t)(e >> 4) * K + kof + (e & 15) * 4);
      }
    }
#pragma unroll
    for (int s = 0; s < 4; s++) {
      short8 af = *(const short8*)&sh.g.As[buf][2 * s + (lane >> 5)][wm * 32 + (lane & 31)][0];
      short8 bf = *(const short8*)&sh.g.Bs[buf][2 * s + (lane >> 5)][wn * 32 + (lane & 31)][0];
      acc = __builtin_amdgcn_mfma_f32_32x32x16_bf16(af, bf, acc, 0, 0, 0);
    }
    __syncthreads();
    if (more) {
      int nb = 1 - buf;
#pragma unroll
      for (int i = 0; i < 2; i++) {
        int e = t + i * 256;
        *(short8*)&sh.g.As[nb][e & 7][e >> 3][0] = areg[i];
      }
#pragma unroll
      for (int i = 0; i < 4; i++) {
        int e = t + i * 256;
        short4v v;
        v[0] = (short)f2bf(breg[i].x); v[1] = (short)f2bf(breg[i].y);
        v[2] = (short)f2bf(breg[i].z); v[3] = (short)f2bf(breg[i].w);
        *(short4v*)&sh.g.Bs[nb][(e & 15) >> 1][e >> 4][((e & 15) & 1) * 4] = v;
      }
      __syncthreads();
    }
  }

  // C/D layout (m74/m101): col=lane&31, row=(reg&3)+8*(reg>>2)+4*(lane>>5)
  int col = nt * 64 + wn * 32 + (lane & 31);
  int rbase = mt * 64 + wm * 32 + 4 * (lane >> 5);
#pragma unroll
  for (int reg = 0; reg < 16; reg++) {
    int row = rbase + (reg & 3) + 8 * (reg >> 2);
    if (row < Mvalid) {
      if (atomicStore) atomicAdd(&C[(size_t)row * N + col], acc[reg]);
      else C[(size_t)row * N + col] = acc[reg];
    }
  }
}

__device__ __forceinline__ float gate_val(const float* sk, int yy, int xx,
                                          float c1w, float c1b, bool use) {
  if (!use) return 1.f;
  float z = sk[yy * HFW + xx] * c1w + c1b;
  return 1.f / (1.f + expf(-z));
}

__global__ __launch_bounds__(256, 1) void mega_kernel(Params p) {
  cg::grid_group grid = cg::this_grid();
  __shared__ SharedU sh;
  int bid = blockIdx.x, t = threadIdx.x;
  int gtid = bid * 256 + t;

  // ================= Phase 0: zero accumulators + transpose + prep ==============
  {
    float4 z4 = make_float4(0.f, 0.f, 0.f, 0.f);
    for (int i = gtid; i < 458752 / 4; i += NTHREADS) ((float4*)p.f5T)[i] = z4;
    for (int i = gtid; i < 32768 / 4; i += NTHREADS) ((float4*)p.out1)[i] = z4;
    if (gtid < 128) p.stats[gtid] = 0.f;

    for (int u = bid; u < 452; u += 256) {
      __syncthreads();
      if (u < 128) {
        // x4 tile: [8][1024][196] f32 -> x4T[b*196+hw][1024] bf16
        int b = u >> 4, cc = u & 15;
        for (int i = t; i < 64 * HW4; i += 256) {
          int c = i / HW4, hw = i - c * HW4;
          sh.tile[c * 201 + hw] = p.x4[((size_t)(b * 1024 + cc * 64 + c)) * HW4 + hw];
        }
        __syncthreads();
        for (int i = t; i < HW4 * 64; i += 256) {
          int hw = i >> 6, c = i & 63;
          p.x4T[((size_t)(b * HW4 + hw)) * 1024 + cc * 64 + c] = f2bf(sh.tile[c * 201 + hw]);
        }
      } else if (u < 384) {
        // x5 tile: [8][2048][49] f32 -> x5T[b*49+hw][2048] bf16
        int u2 = u - 128;
        int b = u2 >> 5, cc = u2 & 31;
        for (int i = t; i < 64 * HW5; i += 256) {
          int c = i / HW5, hw = i - c * HW5;
          sh.tile[c * 51 + hw] = p.x5[((size_t)(b * 2048 + cc * 64 + c)) * HW5 + hw];
        }
        __syncthreads();
        for (int i = t; i < HW5 * 64; i += 256) {
          int hw = i >> 6, c = i & 63;
          p.x5T[((size_t)(b * HW5 + hw)) * 2048 + cc * 64 + c] = f2bf(sh.tile[c * 51 + hw]);
        }
      } else if (u < 448) {
        // ROI descriptor for bg = u-384 (threads 0..24 active)
        int bg = u - 384;
        if (t < 25) {
          int b = bg >> 3;
          int i1 = p.group[bg * 2 + 0], i2 = p.group[bg * 2 + 1];
          const float* bb1 = p.boxes + (size_t)(b * 16 + i1) * 4;
          const float* bb2 = p.boxes + (size_t)(b * 16 + i2) * 4;
          float ux1 = fminf(bb1[0], bb2[0]);
          float uy1 = fminf(bb1[1], bb2[1]);
          float ux2 = fmaxf(bb1[2], bb2[2]);
          float uy2 = fmaxf(bb1[3], bb2[3]);
          float rw = fmaxf(ux2 - ux1, 1.0f), rh = fmaxf(uy2 - uy1, 1.0f);
          int iy = t / 5, ix = t % 5;
          float sy = uy1 + (iy + 0.5f) * (rh * 0.2f);
          float sx = ux1 + (ix + 0.5f) * (rw * 0.2f);
          float valid = (sy >= -1.0f && sy <= 28.0f && sx >= -1.0f && sx <= 28.0f) ? 1.f : 0.f;
          float y = fminf(fmaxf(sy, 0.f), 27.f);
          float x = fminf(fmaxf(sx, 0.f), 27.f);
          int y0 = (int)floorf(y), x0 = (int)floorf(x);
          int y1 = min(y0 + 1, 27), x1 = min(x0 + 1, 27);
          float ly = y - (float)y0, lx = x - (float)x0;
          bool use = (p.label[bg] != -1);
          float c1w = p.c1w[0], c1b = p.c1b[0];
          const float* sk = p.skel + (size_t)bg * NPIX;
          int idx = (bg * 25 + t) * 4;
          p.descw[idx + 0] = (1.f - ly) * (1.f - lx) * valid * gate_val(sk, y0, x0, c1w, c1b, use);
          p.descw[idx + 1] = (1.f - ly) * lx * valid * gate_val(sk, y0, x1, c1w, c1b, use);
          p.descw[idx + 2] = ly * (1.f - lx) * valid * gate_val(sk, y1, x0, c1w, c1b, use);
          p.descw[idx + 3] = ly * lx * valid * gate_val(sk, y1, x1, c1w, c1b, use);
          p.desco[idx + 0] = y0 * HFW + x0;
          p.desco[idx + 1] = y0 * HFW + x1;
          p.desco[idx + 2] = y1 * HFW + x0;
          p.desco[idx + 3] = y1 * HFW + x1;
        }
      } else {
        // resize taps for pix block u-448 (threads 0..195)
        int pix = (u - 448) * 196 + t;
        if (t < 196) {
          int y = pix / HFW, x = pix % HFW;
          {
            float sy = y * (13.0f / 27.0f), sx = x * (13.0f / 27.0f);
            int y0 = (int)sy, x0 = (int)sx;
            int y1 = min(y0 + 1, 13), x1 = min(x0 + 1, 13);
            float ly = sy - y0, lx = sx - x0;
            p.tap4o[pix * 4 + 0] = y0 * 14 + x0; p.tap4w[pix * 4 + 0] = (1.f - ly) * (1.f - lx);
            p.tap4o[pix * 4 + 1] = y0 * 14 + x1; p.tap4w[pix * 4 + 1] = (1.f - ly) * lx;
            p.tap4o[pix * 4 + 2] = y1 * 14 + x0; p.tap4w[pix * 4 + 2] = ly * (1.f - lx);
            p.tap4o[pix * 4 + 3] = y1 * 14 + x1; p.tap4w[pix * 4 + 3] = ly * lx;
          }
          {
            float sy = y * (6.0f / 27.0f), sx = x * (6.0f / 27.0f);
            int y0 = (int)sy, x0 = (int)sx;
            int y1 = min(y0 + 1, 6), x1 = min(x0 + 1, 6);
            float ly = sy - y0, lx = sx - x0;
            p.tap5o[pix * 4 + 0] = y0 * 7 + x0; p.tap5w[pix * 4 + 0] = (1.f - ly) * (1.f - lx);
            p.tap5o[pix * 4 + 1] = y0 * 7 + x1; p.tap5w[pix * 4 + 1] = (1.f - ly) * lx;
            p.tap5o[pix * 4 + 2] = y1 * 7 + x0; p.tap5w[pix * 4 + 2] = ly * (1.f - lx);
            p.tap5o[pix * 4 + 3] = y1 * 7 + x1; p.tap5w[pix * 4 + 3] = ly * lx;
          }
        }
      }
    }
  }
  __threadfence();
  grid.sync();

  // ================= Phase 1: conv4 (200 tiles) + conv5 (224 tiles, split 2) ====
  for (int u = bid; u < 424; u += 256) {
    __syncthreads();
    if (u < 200) {
      int mt = u % 25, nt = u / 25;
      gemm_unit(sh, p.x4T, p.w2c, p.f4T, mt, nt, 0, 1024, 1024, 512, 1568, false);
    } else {
      int u2 = u - 200;
      int mt = u2 % 7, r = u2 / 7;
      int nt = r & 15, sp = r >> 4;
      gemm_unit(sh, p.x5T, p.w3c, p.f5T, mt, nt, sp * 1024, 1024, 2048, 1024, 392, true);
    }
  }
  __threadfence();
  grid.sync();

  // ================= Phase 2: fused resize+ROI + LN1 partial stats ==============
  for (int u = bid; u < 1600; u += 256) {
    __syncthreads();
    int pp = u % 25, bg = u / 25, b = bg >> 3;
    int di = (bg * 25 + pp) * 4;
    if (t < 16) {
      int i = t >> 2, j = t & 3;
      float wg = p.descw[di + i];
      int pix = p.desco[di + i];
      sh.roi.cw4[t] = wg * p.tap4w[pix * 4 + j];
      sh.roi.co4[t] = (b * HW4 + p.tap4o[pix * 4 + j]) * 512;
      sh.roi.cw5[t] = wg * p.tap5w[pix * 4 + j];
      sh.roi.co5[t] = (b * HW5 + p.tap5o[pix * 4 + j]) * 1024;
    }
    if (t == 16) sh.roi.wgs = p.descw[di] + p.descw[di + 1] + p.descw[di + 2] + p.descw[di + 3];
    __syncthreads();
    float w4r[16], w5r[16];
    int o4r[16], o5r[16];
    float wg = sh.roi.wgs;
#pragma unroll
    for (int i = 0; i < 16; i++) {
      w4r[i] = sh.roi.cw4[i]; o4r[i] = sh.roi.co4[i];
      w5r[i] = sh.roi.cw5[i]; o5r[i] = sh.roi.co5[i];
    }
    float ls = 0.f, ls2 = 0.f;
    float* outp = p.roisP + (size_t)(bg * 25 + pp) * CAPP;
    for (int c = t; c < 512; c += 256) {
      float acc = wg * p.b2c[c];
#pragma unroll
      for (int i = 0; i < 16; i++) acc = fmaf(w4r[i], p.f4T[o4r[i] + c], acc);
      outp[c] = acc;
      ls += acc; ls2 = fmaf(acc, acc, ls2);
    }
    for (int c = t; c < 1024; c += 256) {
      float acc = wg * p.b3c[c];
#pragma unroll
      for (int i = 0; i < 16; i++) acc = fmaf(w5r[i], p.f5T[o5r[i] + c], acc);
      outp[512 + c] = acc;
      ls += acc; ls2 = fmaf(acc, acc, ls2);
    }
    for (int off = 32; off; off >>= 1) {
      ls += __shfl_down(ls, off);
      ls2 += __shfl_down(ls2, off);
    }
    int wv = t >> 6;
    if ((t & 63) == 0) { sh.roi.red[wv] = ls; sh.roi.red[4 + wv] = ls2; }
    __syncthreads();
    if (t == 0) {
      atomicAdd(&p.stats[bg * 2 + 0], sh.roi.red[0] + sh.roi.red[1] + sh.roi.red[2] + sh.roi.red[3]);
      atomicAdd(&p.stats[bg * 2 + 1], sh.roi.red[4] + sh.roi.red[5] + sh.roi.red[6] + sh.roi.red[7]);
    }
  }
  __threadfence();
  grid.sync();

  // ================= Phase 3: LN1 apply + ReLU -> sknT bf16 [r][k] ==============
  for (int o = gtid; o < NR * D1; o += NTHREADS) {
    int r = o / D1;
    int k = o - r * D1;
    unsigned c = (unsigned)k / 25u;
    unsigned pp = (unsigned)k - c * 25u;
    float x = p.roisP[((size_t)(r * 25 + pp)) * CAPP + c];
    float S = p.stats[r * 2], S2 = p.stats[r * 2 + 1];
    float mu = S * (1.f / D1);
    float var = S2 * (1.f / D1) - mu * mu;
    float rs = rsqrtf(var + 1e-5f);
    float v = fmaf((x - mu) * rs, p.n1w[k], p.n1b[k]);
    p.sknT[o] = f2bf(fmaxf(v, 0.f));
  }
  __threadfence();
  grid.sync();

  // ================= Phase 4: fc1 (8 ntiles x 40 k-splits of 960) ===============
  for (int u = bid; u < 320; u += 256) {
    __syncthreads();
    int nt = u & 7, sp = u >> 3;
    gemm_unit(sh, p.sknT, p.fw1, p.out1, 0, nt, sp * 960, 960, 38400, 512, 64, true);
  }
  __threadfence();
  grid.sync();

  // ================= Phase 5: LN2 + fc2 (blocks 0..63) ==========================
  if (bid < NR) {
    int r = bid;
    int j1 = t, j2 = t + 256;
    float v1 = p.out1[r * 512 + j1] + p.fb1[j1];
    float v2 = p.out1[r * 512 + j2] + p.fb1[j2];
    float s = v1 + v2, s2 = v1 * v1 + v2 * v2;
    for (int off = 32; off; off >>= 1) {
      s += __shfl_down(s, off);
      s2 += __shfl_down(s2, off);
    }
    int wv = t >> 6;
    if ((t & 63) == 0) { sh.ln.red[wv] = s; sh.ln.red[4 + wv] = s2; }
    __syncthreads();
    float S = sh.ln.red[0] + sh.ln.red[1] + sh.ln.red[2] + sh.ln.red[3];
    float S2 = sh.ln.red[4] + sh.ln.red[5] + sh.ln.red[6] + sh.ln.red[7];
    float mu = S / 512.f;
    float var = S2 / 512.f - mu * mu;
    float rs = rsqrtf(var + 1e-5f);
    float n1v = fmaf((v1 - mu) * rs, p.n2w[j1], p.n2b[j1]);
    float n2v = fmaf((v2 - mu) * rs, p.n2w[j2], p.n2b[j2]);
    float pm[6];
#pragma unroll
    for (int m = 0; m < 6; m++)
      pm[m] = n1v * p.fw2[m * 512 + j1] + n2v * p.fw2[m * 512 + j2];
#pragma unroll
    for (int m = 0; m < 6; m++)
      for (int off = 32; off; off >>= 1) pm[m] += __shfl_down(pm[m], off);
    if ((t & 63) == 0) {
#pragma unroll
      for (int m = 0; m < 6; m++) sh.ln.red2[wv * 6 + m] = pm[m];
    }
    __syncthreads();
    if (t < 6)
      p.out[r * 6 + t] = sh.ln.red2[t] + sh.ln.red2[6 + t] + sh.ln.red2[12 + t] +
                         sh.ln.red2[18 + t] + p.fb2[t];
  }
}

extern "C" void kernel_launch(void* const* d_in, const int* in_sizes, int n_in,
                              void* d_out, int out_size, void* d_ws, size_t ws_size,
                              hipStream_t stream) {
  Params p;
  p.x4    = (const float*)d_in[0];
  p.x5    = (const float*)d_in[1];
  p.boxes = (const float*)d_in[2];
  p.skel  = (const float*)d_in[3];
  p.group = (const int*)d_in[4];
  p.label = (const int*)d_in[6];
  p.c1w   = (const float*)d_in[7];
  p.c1b   = (const float*)d_in[8];
  p.w2c   = (const float*)d_in[9];
  p.b2c   = (const float*)d_in[10];
  p.w3c   = (const float*)d_in[11];
  p.b3c   = (const float*)d_in[12];
  p.n1w   = (const float*)d_in[13];
  p.n1b   = (const float*)d_in[14];
  p.n2w   = (const float*)d_in[15];
  p.n2b   = (const float*)d_in[16];
  p.fw1   = (const float*)d_in[17];
  p.fb1   = (const float*)d_in[18];
  p.fw2   = (const float*)d_in[19];
  p.fb2   = (const float*)d_in[20];
  p.out   = (float*)d_out;

  // workspace layout — ALL offsets in FLOAT units.
  float* ws = (float*)d_ws;
  p.x4T   = (unsigned short*)ws;              // 1600*1024 sh = 819200 f
  p.x5T   = (unsigned short*)(ws + 819200);   // 448*2048 sh  = 458752 f
  p.f4T   = ws + 1277952;                     // 1600*512  = 819,200 (1568 valid)
  p.f5T   = ws + 2097152;                     // 448*1024  = 458,752 (392 valid)
  p.tap4w = ws + 2555904;                     // 3136
  p.tap4o = (int*)(ws + 2559040);             // 3136
  p.tap5w = ws + 2562176;                     // 3136
  p.tap5o = (int*)(ws + 2565312);             // 3136
  p.descw = ws + 2568448;                     // 6400
  p.desco = (int*)(ws + 2574848);             // 6400
  p.roisP = ws + 2581248;                     // 64*25*1536 = 2,457,600
  p.stats = ws + 5038848;                     // 128 (raw S, S2 per row)
  p.sknT  = (unsigned short*)(ws + 5038976);  // 64*38400 sh = 1,228,800 f
  p.out1  = ws + 6267776;                     // 64*512 = 32,768 (end 6,300,544 f)

  void* args[] = { (void*)&p };
  hipLaunchCooperativeKernel((const void*)mega_kernel, dim3(256), dim3(256),
                             args, 0, stream);
}

// Round 8
// 259.680 us; speedup vs baseline: 2.2192x; 2.2192x over previous
//
#include <hip/hip_runtime.h>
#include <hip/hip_cooperative_groups.h>
#include <math.h>

namespace cg = cooperative_groups;

// Problem constants
#define B8   8
#define HW4  196   // 14*14
#define HW5  49    // 7*7
#define HFW  28
#define NPIX 784   // 28*28
#define CAPP 1536
#define D1   38400 // 1536*25
#define NR   64    // B*G

typedef short short8 __attribute__((ext_vector_type(8)));
typedef short short4v __attribute__((ext_vector_type(4)));
typedef float floatx16 __attribute__((ext_vector_type(16)));

__device__ __forceinline__ unsigned short f2bf(float f) {
  unsigned u = __float_as_uint(f);
  u += 0x7FFF + ((u >> 16) & 1);
  return (unsigned short)(u >> 16);
}

struct Params {
  const float *x4, *x5, *boxes, *skel;
  const int *group, *label;
  const float *c1w, *c1b, *w2c, *b2c, *w3c, *b3c;
  const float *n1w, *n1b, *n2w, *n2b, *fw1, *fb1, *fw2, *fb2;
  float* out;
  unsigned short *x4T, *x5T, *sknT;
  float *f4T, *f5T, *tap4w, *tap5w, *descw, *roisP, *stats, *out1;
  int *tap4o, *tap5o, *desco;
};

union SharedU {
  float tile[32 * 201];                 // 25,728 B (transpose phase)
  struct {
    unsigned short As[2][4096];         // [buf][ko*512 + (m^ko)*8]  8 ko-planes
    unsigned short Bs[2][4096];         // [buf][ko*512 + (n^ko)*8 + half*4]
  } g;                                  // 32,768 B total (union max)
  struct {
    float cw4[16], cw5[16], wgs;
    int co4[16], co5[16];
    float red[8];
  } roi;
  struct {
    float red[8];
    float red2[24];
  } ln;
};

// ---- one 64m x 64n GEMM tile: C[m][n] += sum_{k0..k0+kchunk} A[m][k]*W[n][k] ----
// A bf16 k-contig rows; W fp32 k-contig rows (cvt bf16 at stage). dbuf LDS, BK=64.
// XOR-swizzled LDS layout breaks the 8-way staging-write bank conflict.
__device__ __forceinline__ void gemm_unit(
    SharedU& sh, const unsigned short* __restrict__ A, const float* __restrict__ Bw,
    float* __restrict__ C, int mt, int nt, int k0, int kchunk,
    int K, int N, int Mvalid) {
  int t = threadIdx.x;
  int wave = t >> 6, lane = t & 63;
  int wm = wave & 1, wn = wave >> 1;
  const unsigned short* Aptr = A + (size_t)(mt * 64) * K + k0;
  const float* Bptr = Bw + (size_t)(nt * 64) * K + k0;
  short8 areg[2];
  float4 breg[4];
  floatx16 acc;
#pragma unroll
  for (int i = 0; i < 16; i++) acc[i] = 0.f;
  int nkb = kchunk >> 6;

  // prologue: stage kb=0
#pragma unroll
  for (int i = 0; i < 2; i++) {
    int e = t + i * 256;
    areg[i] = *(const short8*)(Aptr + (size_t)(e >> 3) * K + (e & 7) * 8);
  }
#pragma unroll
  for (int i = 0; i < 4; i++) {
    int e = t + i * 256;
    breg[i] = *(const float4*)(Bptr + (size_t)(e >> 4) * K + (e & 15) * 4);
  }
#pragma unroll
  for (int i = 0; i < 2; i++) {
    int e = t + i * 256;
    int m = e >> 3, ko = e & 7;
    *(short8*)&sh.g.As[0][ko * 512 + ((m ^ ko)) * 8] = areg[i];
  }
#pragma unroll
  for (int i = 0; i < 4; i++) {
    int e = t + i * 256;
    short4v v;
    v[0] = (short)f2bf(breg[i].x); v[1] = (short)f2bf(breg[i].y);
    v[2] = (short)f2bf(breg[i].z); v[3] = (short)f2bf(breg[i].w);
    int ko = (e & 15) >> 1, half = (e & 15) & 1, n = e >> 4;
    *(short4v*)&sh.g.Bs[0][ko * 512 + ((n ^ ko)) * 8 + half * 4] = v;
  }
  __syncthreads();

  for (int kb = 0; kb < nkb; kb++) {
    int buf = kb & 1;
    bool more = (kb + 1) < nkb;
    if (more) {
      int kof = (kb + 1) * 64;
#pragma unroll
      for (int i = 0; i < 2; i++) {
        int e = t + i * 256;
        areg[i] = *(const short8*)(Aptr + (size_t)(e >> 3) * K + kof + (e & 7) * 8);
      }
#pragma unroll
      for (int i = 0; i < 4; i++) {
        int e = t + i * 256;
        breg[i] = *(const float4*)(Bptr + (size_t)(e >> 4) * K + kof + (e & 15) * 4);
      }
    }
#pragma unroll
    for (int s = 0; s < 4; s++) {
      int ko = 2 * s + (lane >> 5);
      int am = wm * 32 + (lane & 31);
      int bn = wn * 32 + (lane & 31);
      short8 af = *(const short8*)&sh.g.As[buf][ko * 512 + ((am ^ ko)) * 8];
      short8 bf = *(const short8*)&sh.g.Bs[buf][ko * 512 + ((bn ^ ko)) * 8];
      acc = __builtin_amdgcn_mfma_f32_32x32x16_bf16(af, bf, acc, 0, 0, 0);
    }
    __syncthreads();
    if (more) {
      int nb2 = 1 - buf;
#pragma unroll
      for (int i = 0; i < 2; i++) {
        int e = t + i * 256;
        int m = e >> 3, ko = e & 7;
        *(short8*)&sh.g.As[nb2][ko * 512 + ((m ^ ko)) * 8] = areg[i];
      }
#pragma unroll
      for (int i = 0; i < 4; i++) {
        int e = t + i * 256;
        short4v v;
        v[0] = (short)f2bf(breg[i].x); v[1] = (short)f2bf(breg[i].y);
        v[2] = (short)f2bf(breg[i].z); v[3] = (short)f2bf(breg[i].w);
        int ko = (e & 15) >> 1, half = (e & 15) & 1, n = e >> 4;
        *(short4v*)&sh.g.Bs[nb2][ko * 512 + ((n ^ ko)) * 8 + half * 4] = v;
      }
      __syncthreads();
    }
  }

  // C/D layout (m74/m101): col=lane&31, row=(reg&3)+8*(reg>>2)+4*(lane>>5)
  int col = nt * 64 + wn * 32 + (lane & 31);
  int rbase = mt * 64 + wm * 32 + 4 * (lane >> 5);
#pragma unroll
  for (int reg = 0; reg < 16; reg++) {
    int row = rbase + (reg & 3) + 8 * (reg >> 2);
    if (row < Mvalid) atomicAdd(&C[(size_t)row * N + col], acc[reg]);
  }
}

__device__ __forceinline__ float gate_val(const float* sk, int yy, int xx,
                                          float c1w, float c1b, bool use) {
  if (!use) return 1.f;
  float z = sk[yy * HFW + xx] * c1w + c1b;
  return 1.f / (1.f + expf(-z));
}

// =============== phase bodies (grid-agnostic, stride = gridDim.x) =================
__device__ void run_phase(const Params& p, int phase, SharedU& sh) {
  int bid = blockIdx.x, t = threadIdx.x, gb = gridDim.x;
  int gtid = bid * 256 + t;
  int nth = gb * 256;

  if (phase == 0) {
    // zero accumulators (f4T+f5T contiguous, out1, stats)
    float4 z4 = make_float4(0.f, 0.f, 0.f, 0.f);
    for (int i = gtid; i < 319488; i += nth) ((float4*)p.f4T)[i] = z4;
    for (int i = gtid; i < 8192; i += nth) ((float4*)p.out1)[i] = z4;
    if (gtid < 128) p.stats[gtid] = 0.f;

    for (int u = bid; u < 836; u += gb) {
      __syncthreads();
      if (u < 256) {
        // x4 tile, 32 channels: b=u>>5, cc=u&31
        int b = u >> 5, cc = u & 31;
        for (int i = t; i < 32 * HW4; i += 256) {
          int c = i / HW4, hw = i - c * HW4;
          sh.tile[c * 201 + hw] = p.x4[((size_t)(b * 1024 + cc * 32 + c)) * HW4 + hw];
        }
        __syncthreads();
        for (int i = t; i < HW4 * 32; i += 256) {
          int hw = i >> 5, c = i & 31;
          p.x4T[((size_t)(b * HW4 + hw)) * 1024 + cc * 32 + c] = f2bf(sh.tile[c * 201 + hw]);
        }
      } else if (u < 768) {
        // x5 tile, 32 channels: u2=u-256, b=u2>>6, cc=u2&63
        int u2 = u - 256;
        int b = u2 >> 6, cc = u2 & 63;
        for (int i = t; i < 32 * HW5; i += 256) {
          int c = i / HW5, hw = i - c * HW5;
          sh.tile[c * 51 + hw] = p.x5[((size_t)(b * 2048 + cc * 32 + c)) * HW5 + hw];
        }
        __syncthreads();
        for (int i = t; i < HW5 * 32; i += 256) {
          int hw = i >> 5, c = i & 31;
          p.x5T[((size_t)(b * HW5 + hw)) * 2048 + cc * 32 + c] = f2bf(sh.tile[c * 51 + hw]);
        }
      } else if (u < 832) {
        // ROI descriptor for bg = u-768 (threads 0..24)
        int bg = u - 768;
        if (t < 25) {
          int b = bg >> 3;
          int i1 = p.group[bg * 2 + 0], i2 = p.group[bg * 2 + 1];
          const float* bb1 = p.boxes + (size_t)(b * 16 + i1) * 4;
          const float* bb2 = p.boxes + (size_t)(b * 16 + i2) * 4;
          float ux1 = fminf(bb1[0], bb2[0]);
          float uy1 = fminf(bb1[1], bb2[1]);
          float ux2 = fmaxf(bb1[2], bb2[2]);
          float uy2 = fmaxf(bb1[3], bb2[3]);
          float rw = fmaxf(ux2 - ux1, 1.0f), rh = fmaxf(uy2 - uy1, 1.0f);
          int iy = t / 5, ix = t % 5;
          float sy = uy1 + (iy + 0.5f) * (rh * 0.2f);
          float sx = ux1 + (ix + 0.5f) * (rw * 0.2f);
          float valid = (sy >= -1.0f && sy <= 28.0f && sx >= -1.0f && sx <= 28.0f) ? 1.f : 0.f;
          float y = fminf(fmaxf(sy, 0.f), 27.f);
          float x = fminf(fmaxf(sx, 0.f), 27.f);
          int y0 = (int)floorf(y), x0 = (int)floorf(x);
          int y1 = min(y0 + 1, 27), x1 = min(x0 + 1, 27);
          float ly = y - (float)y0, lx = x - (float)x0;
          bool use = (p.label[bg] != -1);
          float c1w = p.c1w[0], c1b = p.c1b[0];
          const float* sk = p.skel + (size_t)bg * NPIX;
          int idx = (bg * 25 + t) * 4;
          p.descw[idx + 0] = (1.f - ly) * (1.f - lx) * valid * gate_val(sk, y0, x0, c1w, c1b, use);
          p.descw[idx + 1] = (1.f - ly) * lx * valid * gate_val(sk, y0, x1, c1w, c1b, use);
          p.descw[idx + 2] = ly * (1.f - lx) * valid * gate_val(sk, y1, x0, c1w, c1b, use);
          p.descw[idx + 3] = ly * lx * valid * gate_val(sk, y1, x1, c1w, c1b, use);
          p.desco[idx + 0] = y0 * HFW + x0;
          p.desco[idx + 1] = y0 * HFW + x1;
          p.desco[idx + 2] = y1 * HFW + x0;
          p.desco[idx + 3] = y1 * HFW + x1;
        }
      } else {
        // resize taps: pix block u-832 (threads 0..195)
        int pix = (u - 832) * 196 + t;
        if (t < 196) {
          int y = pix / HFW, x = pix % HFW;
          {
            float sy = y * (13.0f / 27.0f), sx = x * (13.0f / 27.0f);
            int y0 = (int)sy, x0 = (int)sx;
            int y1 = min(y0 + 1, 13), x1 = min(x0 + 1, 13);
            float ly = sy - y0, lx = sx - x0;
            p.tap4o[pix * 4 + 0] = y0 * 14 + x0; p.tap4w[pix * 4 + 0] = (1.f - ly) * (1.f - lx);
            p.tap4o[pix * 4 + 1] = y0 * 14 + x1; p.tap4w[pix * 4 + 1] = (1.f - ly) * lx;
            p.tap4o[pix * 4 + 2] = y1 * 14 + x0; p.tap4w[pix * 4 + 2] = ly * (1.f - lx);
            p.tap4o[pix * 4 + 3] = y1 * 14 + x1; p.tap4w[pix * 4 + 3] = ly * lx;
          }
          {
            float sy = y * (6.0f / 27.0f), sx = x * (6.0f / 27.0f);
            int y0 = (int)sy, x0 = (int)sx;
            int y1 = min(y0 + 1, 6), x1 = min(x0 + 1, 6);
            float ly = sy - y0, lx = sx - x0;
            p.tap5o[pix * 4 + 0] = y0 * 7 + x0; p.tap5w[pix * 4 + 0] = (1.f - ly) * (1.f - lx);
            p.tap5o[pix * 4 + 1] = y0 * 7 + x1; p.tap5w[pix * 4 + 1] = (1.f - ly) * lx;
            p.tap5o[pix * 4 + 2] = y1 * 7 + x0; p.tap5w[pix * 4 + 2] = ly * (1.f - lx);
            p.tap5o[pix * 4 + 3] = y1 * 7 + x1; p.tap5w[pix * 4 + 3] = ly * lx;
          }
        }
      }
    }

  } else if (phase == 1) {
    // conv4 (800 units: 25mt x 8nt x 4sp, kchunk 256) + conv5 (896: 7 x 16 x 8)
    for (int u = bid; u < 1696; u += gb) {
      __syncthreads();
      if (u < 800) {
        int mt = u % 25, r = u / 25;
        int nt = r & 7, sp = r >> 3;
        gemm_unit(sh, p.x4T, p.w2c, p.f4T, mt, nt, sp * 256, 256, 1024, 512, 1568);
      } else {
        int u2 = u - 800;
        int mt = u2 % 7, r = u2 / 7;
        int nt = r & 15, sp = r >> 4;
        gemm_unit(sh, p.x5T, p.w3c, p.f5T, mt, nt, sp * 256, 256, 2048, 1024, 392);
      }
    }

  } else if (phase == 2) {
    // fused resize+ROI + LN1 partial stats (1600 units)
    for (int u = bid; u < 1600; u += gb) {
      __syncthreads();
      int pp = u % 25, bg = u / 25, b = bg >> 3;
      int di = (bg * 25 + pp) * 4;
      if (t < 16) {
        int i = t >> 2, j = t & 3;
        float wg = p.descw[di + i];
        int pix = p.desco[di + i];
        sh.roi.cw4[t] = wg * p.tap4w[pix * 4 + j];
        sh.roi.co4[t] = (b * HW4 + p.tap4o[pix * 4 + j]) * 512;
        sh.roi.cw5[t] = wg * p.tap5w[pix * 4 + j];
        sh.roi.co5[t] = (b * HW5 + p.tap5o[pix * 4 + j]) * 1024;
      }
      if (t == 16) sh.roi.wgs = p.descw[di] + p.descw[di + 1] + p.descw[di + 2] + p.descw[di + 3];
      __syncthreads();
      float w4r[16], w5r[16];
      int o4r[16], o5r[16];
      float wg = sh.roi.wgs;
#pragma unroll
      for (int i = 0; i < 16; i++) {
        w4r[i] = sh.roi.cw4[i]; o4r[i] = sh.roi.co4[i];
        w5r[i] = sh.roi.cw5[i]; o5r[i] = sh.roi.co5[i];
      }
      float ls = 0.f, ls2 = 0.f;
      float* outp = p.roisP + (size_t)(bg * 25 + pp) * CAPP;
      for (int c = t; c < 512; c += 256) {
        float acc = wg * p.b2c[c];
#pragma unroll
        for (int i = 0; i < 16; i++) acc = fmaf(w4r[i], p.f4T[o4r[i] + c], acc);
        outp[c] = acc;
        ls += acc; ls2 = fmaf(acc, acc, ls2);
      }
      for (int c = t; c < 1024; c += 256) {
        float acc = wg * p.b3c[c];
#pragma unroll
        for (int i = 0; i < 16; i++) acc = fmaf(w5r[i], p.f5T[o5r[i] + c], acc);
        outp[512 + c] = acc;
        ls += acc; ls2 = fmaf(acc, acc, ls2);
      }
      for (int off = 32; off; off >>= 1) {
        ls += __shfl_down(ls, off);
        ls2 += __shfl_down(ls2, off);
      }
      int wv = t >> 6;
      if ((t & 63) == 0) { sh.roi.red[wv] = ls; sh.roi.red[4 + wv] = ls2; }
      __syncthreads();
      if (t == 0) {
        atomicAdd(&p.stats[bg * 2 + 0], sh.roi.red[0] + sh.roi.red[1] + sh.roi.red[2] + sh.roi.red[3]);
        atomicAdd(&p.stats[bg * 2 + 1], sh.roi.red[4] + sh.roi.red[5] + sh.roi.red[6] + sh.roi.red[7]);
      }
    }

  } else if (phase == 3) {
    // LN1 apply + ReLU -> sknT bf16 [r][k]
    for (int o = gtid; o < NR * D1; o += nth) {
      int r = o / D1;
      int k = o - r * D1;
      unsigned c = (unsigned)k / 25u;
      unsigned pp = (unsigned)k - c * 25u;
      float x = p.roisP[((size_t)(r * 25 + pp)) * CAPP + c];
      float S = p.stats[r * 2], S2 = p.stats[r * 2 + 1];
      float mu = S * (1.f / D1);
      float var = S2 * (1.f / D1) - mu * mu;
      float rs = rsqrtf(var + 1e-5f);
      float v = fmaf((x - mu) * rs, p.n1w[k], p.n1b[k]);
      p.sknT[o] = f2bf(fmaxf(v, 0.f));
    }

  } else if (phase == 4) {
    // fc1: 8 ntiles x 120 k-splits of 320
    for (int u = bid; u < 960; u += gb) {
      __syncthreads();
      int nt = u & 7, sp = u >> 3;
      gemm_unit(sh, p.sknT, p.fw1, p.out1, 0, nt, sp * 320, 320, 38400, 512, 64);
    }

  } else {
    // LN2 + fc2
    for (int r = bid; r < NR; r += gb) {
      __syncthreads();
      int j1 = t, j2 = t + 256;
      float v1 = p.out1[r * 512 + j1] + p.fb1[j1];
      float v2 = p.out1[r * 512 + j2] + p.fb1[j2];
      float s = v1 + v2, s2 = v1 * v1 + v2 * v2;
      for (int off = 32; off; off >>= 1) {
        s += __shfl_down(s, off);
        s2 += __shfl_down(s2, off);
      }
      int wv = t >> 6;
      if ((t & 63) == 0) { sh.ln.red[wv] = s; sh.ln.red[4 + wv] = s2; }
      __syncthreads();
      float S = sh.ln.red[0] + sh.ln.red[1] + sh.ln.red[2] + sh.ln.red[3];
      float S2 = sh.ln.red[4] + sh.ln.red[5] + sh.ln.red[6] + sh.ln.red[7];
      float mu = S / 512.f;
      float var = S2 / 512.f - mu * mu;
      float rs = rsqrtf(var + 1e-5f);
      float n1v = fmaf((v1 - mu) * rs, p.n2w[j1], p.n2b[j1]);
      float n2v = fmaf((v2 - mu) * rs, p.n2w[j2], p.n2b[j2]);
      float pm[6];
#pragma unroll
      for (int m = 0; m < 6; m++)
        pm[m] = n1v * p.fw2[m * 512 + j1] + n2v * p.fw2[m * 512 + j2];
#pragma unroll
      for (int m = 0; m < 6; m++)
        for (int off = 32; off; off >>= 1) pm[m] += __shfl_down(pm[m], off);
      if ((t & 63) == 0) {
#pragma unroll
        for (int m = 0; m < 6; m++) sh.ln.red2[wv * 6 + m] = pm[m];
      }
      __syncthreads();
      if (t < 6)
        p.out[r * 6 + t] = sh.ln.red2[t] + sh.ln.red2[6 + t] + sh.ln.red2[12 + t] +
                           sh.ln.red2[18 + t] + p.fb2[t];
    }
  }
}

__global__ __launch_bounds__(256, 4) void mega_kernel(Params p) {
  cg::grid_group grid = cg::this_grid();
  __shared__ SharedU sh;
  run_phase(p, 0, sh);
  __threadfence(); grid.sync();
  run_phase(p, 1, sh);
  __threadfence(); grid.sync();
  run_phase(p, 2, sh);
  __threadfence(); grid.sync();
  run_phase(p, 3, sh);
  __threadfence(); grid.sync();
  run_phase(p, 4, sh);
  __threadfence(); grid.sync();
  run_phase(p, 5, sh);
}

__global__ __launch_bounds__(256, 4) void phase_kernel(Params p, int phase) {
  __shared__ SharedU sh;
  run_phase(p, phase, sh);
}

extern "C" void kernel_launch(void* const* d_in, const int* in_sizes, int n_in,
                              void* d_out, int out_size, void* d_ws, size_t ws_size,
                              hipStream_t stream) {
  Params p;
  p.x4    = (const float*)d_in[0];
  p.x5    = (const float*)d_in[1];
  p.boxes = (const float*)d_in[2];
  p.skel  = (const float*)d_in[3];
  p.group = (const int*)d_in[4];
  p.label = (const int*)d_in[6];
  p.c1w   = (const float*)d_in[7];
  p.c1b   = (const float*)d_in[8];
  p.w2c   = (const float*)d_in[9];
  p.b2c   = (const float*)d_in[10];
  p.w3c   = (const float*)d_in[11];
  p.b3c   = (const float*)d_in[12];
  p.n1w   = (const float*)d_in[13];
  p.n1b   = (const float*)d_in[14];
  p.n2w   = (const float*)d_in[15];
  p.n2b   = (const float*)d_in[16];
  p.fw1   = (const float*)d_in[17];
  p.fb1   = (const float*)d_in[18];
  p.fw2   = (const float*)d_in[19];
  p.fb2   = (const float*)d_in[20];
  p.out   = (float*)d_out;

  // workspace layout — ALL offsets in FLOAT units.
  float* ws = (float*)d_ws;
  p.x4T   = (unsigned short*)ws;              // 1600*1024 sh = 819200 f
  p.x5T   = (unsigned short*)(ws + 819200);   // 448*2048 sh  = 458752 f
  p.f4T   = ws + 1277952;                     // 1600*512  = 819,200 (1568 valid)
  p.f5T   = ws + 2097152;                     // 448*1024  = 458,752 (392 valid)
  p.tap4w = ws + 2555904;                     // 3136
  p.tap4o = (int*)(ws + 2559040);             // 3136
  p.tap5w = ws + 2562176;                     // 3136
  p.tap5o = (int*)(ws + 2565312);             // 3136
  p.descw = ws + 2568448;                     // 6400
  p.desco = (int*)(ws + 2574848);             // 6400
  p.roisP = ws + 2581248;                     // 64*25*1536 = 2,457,600
  p.stats = ws + 5038848;                     // 128 (raw S, S2 per row)
  p.sknT  = (unsigned short*)(ws + 5038976);  // 64*38400 sh = 1,228,800 f
  p.out1  = ws + 6267776;                     // 64*512 = 32,768 (end 6,300,544 f)

  // Query true co-residency (round-7 lesson: never assume it).
  int nb = 0;
  hipError_t e = hipOccupancyMaxActiveBlocksPerMultiprocessor(
      &nb, (const void*)mega_kernel, 256, 0);
  int grid = (e == hipSuccess) ? nb * 256 : 0;

  if (grid >= 768) {
    if (grid > 1024) grid = 1024;
    void* args[] = { (void*)&p };
    hipLaunchCooperativeKernel((const void*)mega_kernel, dim3(grid), dim3(256),
                               args, 0, stream);
  } else {
    // fallback: same phase code, 6 plain wide-grid dispatches
    phase_kernel<<<836, 256, 0, stream>>>(p, 0);
    phase_kernel<<<1696, 256, 0, stream>>>(p, 1);
    phase_kernel<<<1600, 256, 0, stream>>>(p, 2);
    phase_kernel<<<9600, 256, 0, stream>>>(p, 3);
    phase_kernel<<<960, 256, 0, stream>>>(p, 4);
    phase_kernel<<<64, 256, 0, stream>>>(p, 5);
  }
}